// Round 3
// baseline (346.574 us; speedup 1.0000x reference)
//
#include <hip/hip_runtime.h>
#include <hip/hip_bf16.h>
#include <hip/hip_cooperative_groups.h>
#include <math.h>

namespace cg = cooperative_groups;

#define D 256
#define HID 16
#define CAP 96

typedef __attribute__((ext_vector_type(8))) short bf16x8;
typedef __attribute__((ext_vector_type(4))) float f32x4;

__device__ __forceinline__ ushort f2b(float x){
  uint u = __float_as_uint(x);
  u = u + 0x7FFFu + ((u >> 16) & 1u);   // round-to-nearest-even
  return (ushort)(u >> 16);
}
__device__ __forceinline__ float b2f(ushort u){ return __uint_as_float(((uint)u) << 16); }

// ---- prep: h->bf16 convert + pack 6 weight matrices + zero cur ----
// packed B layout (nt-major; 64-col tile = contiguous 32KB chunk):
// pb[((nt*8 + kt)*64 + lane)*8 + i] = W[kt*32 + (lane>>4)*8 + i][nt*16 + (lane&15)]
__global__ void prep_kernel(const float* h, ushort* Hbf, int NC,
                            const float* Wm1, const float* Wm2,
                            const float* Wu1, const float* Wu2,
                            ushort* pAll, int* cur, int N){
  int total = NC + 6 * 65536 + N;
  for (int idx = blockIdx.x * blockDim.x + threadIdx.x; idx < total;
       idx += gridDim.x * blockDim.x){
    if (idx < NC){ Hbf[idx] = f2b(h[idx]); continue; }
    int q = idx - NC;
    if (q < 6 * 65536){
      int mat = q >> 16, p = q & 65535;
      int i = p & 7, l = (p >> 3) & 63, kt = (p >> 9) & 7, nt = p >> 12;
      int k = kt * 32 + ((l >> 4) * 8) + i;
      int n = nt * 16 + (l & 15);
      const float* src;
      switch (mat){
        case 0: src = Wm1 + (size_t)k * 256 + n; break;            // Wm1a
        case 1: src = Wm1 + (size_t)(256 + k) * 256 + n; break;    // Wm1b
        case 2: src = Wm2 + (size_t)k * 256 + n; break;
        case 3: src = Wu1 + (size_t)k * 256 + n; break;            // Wu1a
        case 4: src = Wu1 + (size_t)(256 + k) * 256 + n; break;    // Wu1b
        default: src = Wu2 + (size_t)k * 256 + n; break;
      }
      pAll[q] = f2b(*src);
      continue;
    }
    q -= 6 * 65536;
    if (q < N) cur[q] = 0;
  }
}

struct MegaArgs {
  const float* h; const int* ei; const int* val;
  const float* Wm1; const float* bm1; const float* bm2;
  const float* bu1; const float* bu2;
  const float* Wa1; const float* ba1; const float* Wa2; const float* ba2;
  const ushort* Hbf; const ushort* pAll;
  float* P1; ushort* P2; ushort* Qbf; float* S; ushort* Hagg; ushort* Tbf;
  int* cur; uint2* elist;
  float* out;
  int N, E, NB;
  int pLo, pHi, multi;
};

__device__ __forceinline__ void stage_chunk(const ushort* src, ushort* lds, int tid){
  #pragma unroll
  for (int c = 0; c < 8; ++c)
    __builtin_amdgcn_global_load_lds(
      (const __attribute__((address_space(1))) uint*)(src + tid * 8 + c * 2048),
      (__attribute__((address_space(3))) uint*)(lds + tid * 8 + c * 2048), 16, 0, 0);
}

__device__ __forceinline__ void gemm_compute(const ushort* A, int r0, int r1, int kl,
                                             const ushort* lds, int lane,
                                             f32x4 acc[2][4]){
  const ushort* ap0 = A + (size_t)r0 * 256 + kl;
  const ushort* ap1 = A + (size_t)r1 * 256 + kl;
  #pragma unroll
  for (int kt = 0; kt < 8; ++kt){
    bf16x8 b0 = *(const bf16x8*)(lds + ((size_t)(0 * 8 + kt) * 64 + lane) * 8);
    bf16x8 b1 = *(const bf16x8*)(lds + ((size_t)(1 * 8 + kt) * 64 + lane) * 8);
    bf16x8 b2 = *(const bf16x8*)(lds + ((size_t)(2 * 8 + kt) * 64 + lane) * 8);
    bf16x8 b3 = *(const bf16x8*)(lds + ((size_t)(3 * 8 + kt) * 64 + lane) * 8);
    bf16x8 a0 = *(const bf16x8*)(ap0 + kt * 32);
    bf16x8 a1 = *(const bf16x8*)(ap1 + kt * 32);
    acc[0][0] = __builtin_amdgcn_mfma_f32_16x16x32_bf16(a0, b0, acc[0][0], 0, 0, 0);
    acc[0][1] = __builtin_amdgcn_mfma_f32_16x16x32_bf16(a0, b1, acc[0][1], 0, 0, 0);
    acc[0][2] = __builtin_amdgcn_mfma_f32_16x16x32_bf16(a0, b2, acc[0][2], 0, 0, 0);
    acc[0][3] = __builtin_amdgcn_mfma_f32_16x16x32_bf16(a0, b3, acc[0][3], 0, 0, 0);
    acc[1][0] = __builtin_amdgcn_mfma_f32_16x16x32_bf16(a1, b0, acc[1][0], 0, 0, 0);
    acc[1][1] = __builtin_amdgcn_mfma_f32_16x16x32_bf16(a1, b1, acc[1][1], 0, 0, 0);
    acc[1][2] = __builtin_amdgcn_mfma_f32_16x16x32_bf16(a1, b2, acc[1][2], 0, 0, 0);
    acc[1][3] = __builtin_amdgcn_mfma_f32_16x16x32_bf16(a1, b3, acc[1][3], 0, 0, 0);
  }
}

// BM=128 x BN=64 tiles, grid-stride over tiles. B staged in LDS (32KB chunk).
template<bool SPLIT, bool RELU, bool DUAL>
__device__ __forceinline__ void gemm_phase(
    int NB, int bid, int tid, int M, int nbn, int ntiles,
    const ushort* A1, const ushort* B1, const ushort* A2, const ushort* B2,
    const float* bias, const float* rowscale, const float* rsvec,
    const float* resid, float* outF, ushort* outB, ushort* lds){
  for (int t = bid; t < ntiles; t += NB){
    int bn = t % nbn, bm = t / nbn;
    stage_chunk(B1 + (size_t)bn * 16384, lds, tid);
    __syncthreads();

    int wave = tid >> 6, lane = tid & 63;
    int rbase = bm * 128 + wave * 32;
    int r0 = min(rbase + (lane & 15), M - 1);
    int r1 = min(rbase + 16 + (lane & 15), M - 1);
    int kl = (lane >> 4) * 8;
    f32x4 zero = {0.f, 0.f, 0.f, 0.f};
    f32x4 acc[2][4];
    #pragma unroll
    for (int x = 0; x < 2; ++x)
      #pragma unroll
      for (int y = 0; y < 4; ++y) acc[x][y] = zero;

    gemm_compute(A1, r0, r1, kl, lds, lane, acc);
    if (DUAL){
      __syncthreads();
      stage_chunk(B2 + (size_t)bn * 16384, lds, tid);
      __syncthreads();
      gemm_compute(A2, r0, r1, kl, lds, lane, acc);
    }

    int coll = lane & 15, rl = (lane >> 4) * 4;
    #pragma unroll
    for (int rt = 0; rt < 2; ++rt){
      #pragma unroll
      for (int n = 0; n < 4; ++n){
        int cg = bn * 64 + n * 16 + coll;
        float bc = bias ? bias[cg] : 0.f;
        float vcv = rowscale ? rsvec[cg] : 0.f;
        #pragma unroll
        for (int j = 0; j < 4; ++j){
          int r = rbase + rt * 16 + rl + j;
          if (r < M){
            float v = acc[rt][n][j] + bc;
            if (rowscale) v += rowscale[r] * vcv;
            if (RELU) v = fmaxf(v, 0.f);
            if (resid) v += resid[(size_t)r * 256 + cg];
            if (SPLIT){
              if (cg < 256) outF[(size_t)r * 256 + cg] = v;
              else outB[(size_t)r * 256 + (cg - 256)] = f2b(v);
            } else {
              if (outF) outF[(size_t)r * 256 + cg] = v;
              if (outB) outB[(size_t)r * 256 + cg] = f2b(v);
            }
          }
        }
      }
    }
    __syncthreads();  // all waves done with LDS before next tile restages
  }
}

__device__ __forceinline__ void fill_run(const MegaArgs& a, int g){
  for (int e = g; e < a.E; e += a.NB * 256){
    int r = a.ei[e], c = a.ei[a.E + e];
    int vri = a.val[r], vci = a.val[c];
    float vr = (float)vri, vc = (float)vci;
    float s = a.ba2[0];
    #pragma unroll
    for (int j = 0; j < HID; ++j){
      float hj = fmaxf(vr * a.Wa1[j] + vc * a.Wa1[HID + j] + a.ba1[j], 0.f);
      s += hj * a.Wa2[j];
    }
    float att = 1.f / (1.f + expf(-s));
    int pos = atomicAdd(&a.cur[r], 1);
    if (pos < CAP)
      a.elist[(size_t)r * CAP + pos] =
          make_uint2((uint)c | ((uint)vci << 16), __float_as_uint(att));
  }
}

__device__ __forceinline__ void phase2_run(const MegaArgs& a, int bid, int tid){
  int wave = tid >> 6, lane = tid & 63;
  int f0 = lane * 4;
  const float* wvr = a.Wm1 + (size_t)512 * 256;
  const float* wvc = a.Wm1 + (size_t)513 * 256;
  float4 wr = *(const float4*)(wvr + f0);
  float4 wv = *(const float4*)(wvc + f0);
  float4 bb = *(const float4*)(a.bm1 + f0);
  int totW = a.NB * 4;
  for (int r = bid * 4 + wave; r < a.N; r += totW){
    float4 p1 = *(const float4*)(a.P1 + (size_t)r * D + f0);
    float vrf = (float)a.val[r];
    float bx = p1.x + vrf * wr.x + bb.x;
    float by = p1.y + vrf * wr.y + bb.y;
    float bz = p1.z + vrf * wr.z + bb.z;
    float bw = p1.w + vrf * wr.w + bb.w;
    float ax = 0.f, ay = 0.f, az = 0.f, aw = 0.f, satt = 0.f;
    int dg = min(a.cur[r], CAP);
    const uint2* el = a.elist + (size_t)r * CAP;
    int e = 0;
    for (; e + 2 <= dg; e += 2){
      uint2 pa = el[e], pb = el[e + 1];
      int ca = (int)(pa.x & 0xFFFFu), cb = (int)(pb.x & 0xFFFFu);
      float vca = (float)(pa.x >> 16), vcb = (float)(pb.x >> 16);
      float atta = __uint_as_float(pa.y), attb = __uint_as_float(pb.y);
      ushort4 va = *(const ushort4*)(a.P2 + (size_t)ca * D + f0);
      ushort4 vb = *(const ushort4*)(a.P2 + (size_t)cb * D + f0);
      float zx = bx + b2f(va.x) + vca * wv.x;
      float zy = by + b2f(va.y) + vca * wv.y;
      float zz = bz + b2f(va.z) + vca * wv.z;
      float zw = bw + b2f(va.w) + vca * wv.w;
      ax += atta * fmaxf(zx, 0.f);
      ay += atta * fmaxf(zy, 0.f);
      az += atta * fmaxf(zz, 0.f);
      aw += atta * fmaxf(zw, 0.f);
      zx = bx + b2f(vb.x) + vcb * wv.x;
      zy = by + b2f(vb.y) + vcb * wv.y;
      zz = bz + b2f(vb.z) + vcb * wv.z;
      zw = bw + b2f(vb.w) + vcb * wv.w;
      ax += attb * fmaxf(zx, 0.f);
      ay += attb * fmaxf(zy, 0.f);
      az += attb * fmaxf(zz, 0.f);
      aw += attb * fmaxf(zw, 0.f);
      satt += atta + attb;
    }
    if (e < dg){
      uint2 pa = el[e];
      int ca = (int)(pa.x & 0xFFFFu);
      float vca = (float)(pa.x >> 16);
      float atta = __uint_as_float(pa.y);
      ushort4 va = *(const ushort4*)(a.P2 + (size_t)ca * D + f0);
      float zx = bx + b2f(va.x) + vca * wv.x;
      float zy = by + b2f(va.y) + vca * wv.y;
      float zz = bz + b2f(va.z) + vca * wv.z;
      float zw = bw + b2f(va.w) + vca * wv.w;
      ax += atta * fmaxf(zx, 0.f);
      ay += atta * fmaxf(zy, 0.f);
      az += atta * fmaxf(zz, 0.f);
      aw += atta * fmaxf(zw, 0.f);
      satt += atta;
    }
    ushort4 qo; qo.x = f2b(ax); qo.y = f2b(ay); qo.z = f2b(az); qo.w = f2b(aw);
    *(ushort4*)(a.Qbf + (size_t)r * D + f0) = qo;
    if (lane == 0) a.S[r] = satt;
  }
}

__global__ __launch_bounds__(256, 3) void mega_kernel(MegaArgs a){
  extern __shared__ ushort lds[];
  int bid = blockIdx.x, tid = threadIdx.x;
  int MB = (a.N + 127) / 128;
  for (int ph = a.pLo; ph <= a.pHi; ++ph){
    if (ph == 0){
      // G1: [P1|P2] = H @ [Wm1a|Wm1b]  (split f32|bf16), plus edge bucketing
      gemm_phase<true, false, false>(a.NB, bid, tid, a.N, 8, MB * 8,
          a.Hbf, a.pAll, nullptr, nullptr,
          nullptr, nullptr, nullptr, nullptr, a.P1, a.P2, lds);
      fill_run(a, bid * 256 + tid);
    } else if (ph == 1){
      phase2_run(a, bid, tid);
    } else if (ph == 2){
      // G2: Hagg = Q @ Wm2 + S*bm2
      gemm_phase<false, false, false>(a.NB, bid, tid, a.N, 4, MB * 4,
          a.Qbf, a.pAll + 2 * 65536, nullptr, nullptr,
          nullptr, a.S, a.bm2, nullptr, nullptr, a.Hagg, lds);
    } else if (ph == 3){
      // G3: T = relu(H@Wu1a + Hagg@Wu1b + bu1)
      gemm_phase<false, true, true>(a.NB, bid, tid, a.N, 4, MB * 4,
          a.Hbf, a.pAll + 3 * 65536, a.Hagg, a.pAll + 4 * 65536,
          a.bu1, nullptr, nullptr, nullptr, nullptr, a.Tbf, lds);
    } else {
      // G4: out = h + T@Wu2 + bu2
      gemm_phase<false, false, false>(a.NB, bid, tid, a.N, 4, MB * 4,
          a.Tbf, a.pAll + 5 * 65536, nullptr, nullptr,
          a.bu2, nullptr, nullptr, a.h, a.out, nullptr, lds);
    }
    if (a.multi && ph < a.pHi) cg::this_grid().sync();
  }
}

extern "C" void kernel_launch(void* const* d_in, const int* in_sizes, int n_in,
                              void* d_out, int out_size, void* d_ws, size_t ws_size,
                              hipStream_t stream){
  const float* h   = (const float*)d_in[0];
  const int*   ei  = (const int*)d_in[1];
  const int*   val = (const int*)d_in[3];
  const float* Wm1 = (const float*)d_in[4];
  const float* bm1 = (const float*)d_in[5];
  const float* Wm2 = (const float*)d_in[6];
  const float* bm2 = (const float*)d_in[7];
  const float* Wu1 = (const float*)d_in[8];
  const float* bu1 = (const float*)d_in[9];
  const float* Wu2 = (const float*)d_in[10];
  const float* bu2 = (const float*)d_in[11];
  const float* Wa1 = (const float*)d_in[12];
  const float* ba1 = (const float*)d_in[13];
  const float* Wa2 = (const float*)d_in[14];
  const float* ba2 = (const float*)d_in[15];
  int N = in_sizes[0] / D;
  int E = in_sizes[1] / 2;

  char* ws = (char*)d_ws;
  size_t o = 0;
  auto alloc = [&](size_t bytes)->char*{
    char* p = ws + o; o += (bytes + 255) & ~(size_t)255; return p;
  };
  float*  P1    = (float*) alloc((size_t)N * D * 4);
  ushort* P2    = (ushort*)alloc((size_t)N * D * 2);
  ushort* Hbf   = (ushort*)alloc((size_t)N * D * 2);
  ushort* Qbf   = (ushort*)alloc((size_t)N * D * 2);
  ushort* Hagg  = (ushort*)alloc((size_t)N * D * 2);
  ushort* Tbf   = (ushort*)alloc((size_t)N * D * 2);
  float*  S     = (float*) alloc((size_t)N * 4);
  int*    cur   = (int*)   alloc((size_t)N * 4);
  uint2*  elist = (uint2*) alloc((size_t)N * CAP * 8);
  ushort* pAll  = (ushort*)alloc((size_t)6 * 65536 * 2);

  int NC = N * D;
  prep_kernel<<<2048, 256, 0, stream>>>(h, Hbf, NC, Wm1, Wm2, Wu1, Wu2, pAll, cur, N);

  int bpc = 0;
  hipError_t qe = hipOccupancyMaxActiveBlocksPerMultiprocessor(&bpc, mega_kernel, 256, 32768);
  if (qe != hipSuccess || bpc < 1) bpc = 1;
  int NB = bpc * 256;
  if (NB > 768) NB = 768;

  MegaArgs a;
  a.h = h; a.ei = ei; a.val = val;
  a.Wm1 = Wm1; a.bm1 = bm1; a.bm2 = bm2;
  a.bu1 = bu1; a.bu2 = bu2;
  a.Wa1 = Wa1; a.ba1 = ba1; a.Wa2 = Wa2; a.ba2 = ba2;
  a.Hbf = Hbf; a.pAll = pAll;
  a.P1 = P1; a.P2 = P2; a.Qbf = Qbf; a.S = S; a.Hagg = Hagg; a.Tbf = Tbf;
  a.cur = cur; a.elist = elist;
  a.out = (float*)d_out;
  a.N = N; a.E = E; a.NB = NB;
  a.pLo = 0; a.pHi = 4; a.multi = 1;

  void* kargs[] = { (void*)&a };
  hipError_t err = hipLaunchCooperativeKernel(mega_kernel, dim3(NB), dim3(256),
                                              kargs, (unsigned)32768, stream);
  if (err != hipSuccess){
    // fallback: phase-per-dispatch (kernel boundaries provide the sync)
    for (int p = 0; p < 5; ++p){
      MegaArgs ap = a; ap.pLo = p; ap.pHi = p; ap.multi = 0;
      mega_kernel<<<NB, 256, 32768, stream>>>(ap);
    }
  }
}

// Round 4
// 117.200 us; speedup vs baseline: 2.9571x; 2.9571x over previous
//
#include <hip/hip_runtime.h>
#include <hip/hip_bf16.h>
#include <math.h>

#define D 256
#define HID 16
#define CAP 96

typedef __attribute__((ext_vector_type(8))) short bf16x8;
typedef __attribute__((ext_vector_type(4))) float f32x4;

__device__ __forceinline__ ushort f2b(float x){
  uint u = __float_as_uint(x);
  u = u + 0x7FFFu + ((u >> 16) & 1u);   // round-to-nearest-even
  return (ushort)(u >> 16);
}
__device__ __forceinline__ float b2f(ushort u){ return __uint_as_float(((uint)u) << 16); }

// ---- prep: h->bf16 convert + pack 6 weight matrices + zero cur ----
// packed B layout (nt-major; 64-col tile = contiguous 32KB chunk):
// pb[((nt*8 + kt)*64 + lane)*8 + i] = W[kt*32 + (lane>>4)*8 + i][nt*16 + (lane&15)]
__global__ void prep_kernel(const float* h, ushort* Hbf, int NC,
                            const float* Wm1, const float* Wm2,
                            const float* Wu1, const float* Wu2,
                            ushort* pAll, int* cur, int N){
  int total = NC + 6 * 65536 + N;
  for (int idx = blockIdx.x * blockDim.x + threadIdx.x; idx < total;
       idx += gridDim.x * blockDim.x){
    if (idx < NC){ Hbf[idx] = f2b(h[idx]); continue; }
    int q = idx - NC;
    if (q < 6 * 65536){
      int mat = q >> 16, p = q & 65535;
      int i = p & 7, l = (p >> 3) & 63, kt = (p >> 9) & 7, nt = p >> 12;
      int k = kt * 32 + ((l >> 4) * 8) + i;
      int n = nt * 16 + (l & 15);
      const float* src;
      switch (mat){
        case 0: src = Wm1 + (size_t)k * 256 + n; break;            // Wm1a
        case 1: src = Wm1 + (size_t)(256 + k) * 256 + n; break;    // Wm1b
        case 2: src = Wm2 + (size_t)k * 256 + n; break;
        case 3: src = Wu1 + (size_t)k * 256 + n; break;            // Wu1a
        case 4: src = Wu1 + (size_t)(256 + k) * 256 + n; break;    // Wu1b
        default: src = Wu2 + (size_t)k * 256 + n; break;
      }
      pAll[q] = f2b(*src);
      continue;
    }
    q -= 6 * 65536;
    if (q < N) cur[q] = 0;
  }
}

__device__ __forceinline__ void stage_chunk(const ushort* src, ushort* lds, int tid){
  #pragma unroll
  for (int c = 0; c < 8; ++c)
    __builtin_amdgcn_global_load_lds(
      (const __attribute__((address_space(1))) uint*)(src + tid * 8 + c * 2048),
      (__attribute__((address_space(3))) uint*)(lds + tid * 8 + c * 2048), 16, 0, 0);
}

__device__ __forceinline__ void gemm_compute(const ushort* A, int r0, int r1, int kl,
                                             const ushort* lds, int lane,
                                             f32x4 acc[2][4]){
  const ushort* ap0 = A + (size_t)r0 * 256 + kl;
  const ushort* ap1 = A + (size_t)r1 * 256 + kl;
  #pragma unroll
  for (int kt = 0; kt < 8; ++kt){
    bf16x8 b0 = *(const bf16x8*)(lds + ((size_t)(0 * 8 + kt) * 64 + lane) * 8);
    bf16x8 b1 = *(const bf16x8*)(lds + ((size_t)(1 * 8 + kt) * 64 + lane) * 8);
    bf16x8 b2 = *(const bf16x8*)(lds + ((size_t)(2 * 8 + kt) * 64 + lane) * 8);
    bf16x8 b3 = *(const bf16x8*)(lds + ((size_t)(3 * 8 + kt) * 64 + lane) * 8);
    bf16x8 a0 = *(const bf16x8*)(ap0 + kt * 32);
    bf16x8 a1 = *(const bf16x8*)(ap1 + kt * 32);
    acc[0][0] = __builtin_amdgcn_mfma_f32_16x16x32_bf16(a0, b0, acc[0][0], 0, 0, 0);
    acc[0][1] = __builtin_amdgcn_mfma_f32_16x16x32_bf16(a0, b1, acc[0][1], 0, 0, 0);
    acc[0][2] = __builtin_amdgcn_mfma_f32_16x16x32_bf16(a0, b2, acc[0][2], 0, 0, 0);
    acc[0][3] = __builtin_amdgcn_mfma_f32_16x16x32_bf16(a0, b3, acc[0][3], 0, 0, 0);
    acc[1][0] = __builtin_amdgcn_mfma_f32_16x16x32_bf16(a1, b0, acc[1][0], 0, 0, 0);
    acc[1][1] = __builtin_amdgcn_mfma_f32_16x16x32_bf16(a1, b1, acc[1][1], 0, 0, 0);
    acc[1][2] = __builtin_amdgcn_mfma_f32_16x16x32_bf16(a1, b2, acc[1][2], 0, 0, 0);
    acc[1][3] = __builtin_amdgcn_mfma_f32_16x16x32_bf16(a1, b3, acc[1][3], 0, 0, 0);
  }
}

// ---- G1 + fill fused: [P1|P2] = H @ [Wm1a|Wm1b] (split f32|bf16), then edge bucketing.
__global__ __launch_bounds__(256) void g1f_kernel(
    const ushort* __restrict__ Hbf, const ushort* __restrict__ B,
    float* __restrict__ P1, ushort* __restrict__ P2,
    const int* __restrict__ ei, const int* __restrict__ val,
    const float* __restrict__ Wa1, const float* __restrict__ ba1,
    const float* __restrict__ Wa2, const float* __restrict__ ba2,
    int* __restrict__ cur, uint2* __restrict__ elist,
    int M, int E, int ntiles){
  extern __shared__ ushort lds[];
  int tid = threadIdx.x;
  for (int t = blockIdx.x; t < ntiles; t += gridDim.x){
    int bn = t % 8, bm = t / 8;
    stage_chunk(B + (size_t)bn * 16384, lds, tid);
    __syncthreads();
    int wave = tid >> 6, lane = tid & 63;
    int rbase = bm * 128 + wave * 32;
    int r0 = min(rbase + (lane & 15), M - 1);
    int r1 = min(rbase + 16 + (lane & 15), M - 1);
    int kl = (lane >> 4) * 8;
    f32x4 zero = {0.f, 0.f, 0.f, 0.f};
    f32x4 acc[2][4];
    #pragma unroll
    for (int x = 0; x < 2; ++x)
      #pragma unroll
      for (int y = 0; y < 4; ++y) acc[x][y] = zero;
    gemm_compute(Hbf, r0, r1, kl, lds, lane, acc);
    int coll = lane & 15, rl = (lane >> 4) * 4;
    #pragma unroll
    for (int rt = 0; rt < 2; ++rt){
      #pragma unroll
      for (int n = 0; n < 4; ++n){
        int cg = bn * 64 + n * 16 + coll;
        #pragma unroll
        for (int j = 0; j < 4; ++j){
          int r = rbase + rt * 16 + rl + j;
          if (r < M){
            float v = acc[rt][n][j];
            if (cg < 256) P1[(size_t)r * 256 + cg] = v;
            else P2[(size_t)r * 256 + (cg - 256)] = f2b(v);
          }
        }
      }
    }
    __syncthreads();
  }
  // fill: bucket edges with inline attention MLP
  for (int e = blockIdx.x * 256 + tid; e < E; e += gridDim.x * 256){
    int r = ei[e], c = ei[E + e];
    int vri = val[r], vci = val[c];
    float vr = (float)vri, vc = (float)vci;
    float s = ba2[0];
    #pragma unroll
    for (int j = 0; j < HID; ++j){
      float hj = fmaxf(vr * Wa1[j] + vc * Wa1[HID + j] + ba1[j], 0.f);
      s += hj * Wa2[j];
    }
    float att = 1.f / (1.f + expf(-s));
    int pos = atomicAdd(&cur[r], 1);
    if (pos < CAP)
      elist[(size_t)r * CAP + pos] =
          make_uint2((uint)c | ((uint)vci << 16), __float_as_uint(att));
  }
}

// ---- phase2: per-row edge aggregation, one wave per row, 4-deep gather pipeline.
__global__ __launch_bounds__(256) void phase2_kernel(
    const float* __restrict__ P1, const ushort* __restrict__ P2,
    const int* __restrict__ cur, const uint2* __restrict__ elist,
    const int* __restrict__ val, const float* __restrict__ Wm1,
    const float* __restrict__ bm1,
    ushort* __restrict__ Qbf, float* __restrict__ S, int N){
  int wave = threadIdx.x >> 6, lane = threadIdx.x & 63;
  int r = blockIdx.x * 4 + wave;
  if (r >= N) return;
  int f0 = lane * 4;
  const float* wvr = Wm1 + (size_t)512 * 256;
  const float* wvc = Wm1 + (size_t)513 * 256;
  float4 p1 = *(const float4*)(P1 + (size_t)r * D + f0);
  float4 wr = *(const float4*)(wvr + f0);
  float4 wv = *(const float4*)(wvc + f0);
  float4 bb = *(const float4*)(bm1 + f0);
  float vrf = (float)val[r];
  float bx = p1.x + vrf * wr.x + bb.x;
  float by = p1.y + vrf * wr.y + bb.y;
  float bz = p1.z + vrf * wr.z + bb.z;
  float bw = p1.w + vrf * wr.w + bb.w;
  float ax = 0.f, ay = 0.f, az = 0.f, aw = 0.f, satt = 0.f;
  int dg = min(cur[r], CAP);
  const uint2* el = elist + (size_t)r * CAP;
  int e = 0;
  for (; e + 4 <= dg; e += 4){
    uint2 q0 = el[e], q1 = el[e + 1], q2 = el[e + 2], q3 = el[e + 3];
    ushort4 v0 = *(const ushort4*)(P2 + (size_t)(q0.x & 0xFFFFu) * D + f0);
    ushort4 v1 = *(const ushort4*)(P2 + (size_t)(q1.x & 0xFFFFu) * D + f0);
    ushort4 v2 = *(const ushort4*)(P2 + (size_t)(q2.x & 0xFFFFu) * D + f0);
    ushort4 v3 = *(const ushort4*)(P2 + (size_t)(q3.x & 0xFFFFu) * D + f0);
    float vc0 = (float)(q0.x >> 16), at0 = __uint_as_float(q0.y);
    float vc1 = (float)(q1.x >> 16), at1 = __uint_as_float(q1.y);
    float vc2 = (float)(q2.x >> 16), at2 = __uint_as_float(q2.y);
    float vc3 = (float)(q3.x >> 16), at3 = __uint_as_float(q3.y);
    ax += at0 * fmaxf(bx + b2f(v0.x) + vc0 * wv.x, 0.f);
    ay += at0 * fmaxf(by + b2f(v0.y) + vc0 * wv.y, 0.f);
    az += at0 * fmaxf(bz + b2f(v0.z) + vc0 * wv.z, 0.f);
    aw += at0 * fmaxf(bw + b2f(v0.w) + vc0 * wv.w, 0.f);
    ax += at1 * fmaxf(bx + b2f(v1.x) + vc1 * wv.x, 0.f);
    ay += at1 * fmaxf(by + b2f(v1.y) + vc1 * wv.y, 0.f);
    az += at1 * fmaxf(bz + b2f(v1.z) + vc1 * wv.z, 0.f);
    aw += at1 * fmaxf(bw + b2f(v1.w) + vc1 * wv.w, 0.f);
    ax += at2 * fmaxf(bx + b2f(v2.x) + vc2 * wv.x, 0.f);
    ay += at2 * fmaxf(by + b2f(v2.y) + vc2 * wv.y, 0.f);
    az += at2 * fmaxf(bz + b2f(v2.z) + vc2 * wv.z, 0.f);
    aw += at2 * fmaxf(bw + b2f(v2.w) + vc2 * wv.w, 0.f);
    ax += at3 * fmaxf(bx + b2f(v3.x) + vc3 * wv.x, 0.f);
    ay += at3 * fmaxf(by + b2f(v3.y) + vc3 * wv.y, 0.f);
    az += at3 * fmaxf(bz + b2f(v3.z) + vc3 * wv.z, 0.f);
    aw += at3 * fmaxf(bw + b2f(v3.w) + vc3 * wv.w, 0.f);
    satt += at0 + at1 + at2 + at3;
  }
  for (; e < dg; ++e){
    uint2 q0 = el[e];
    ushort4 v0 = *(const ushort4*)(P2 + (size_t)(q0.x & 0xFFFFu) * D + f0);
    float vc0 = (float)(q0.x >> 16), at0 = __uint_as_float(q0.y);
    ax += at0 * fmaxf(bx + b2f(v0.x) + vc0 * wv.x, 0.f);
    ay += at0 * fmaxf(by + b2f(v0.y) + vc0 * wv.y, 0.f);
    az += at0 * fmaxf(bz + b2f(v0.z) + vc0 * wv.z, 0.f);
    aw += at0 * fmaxf(bw + b2f(v0.w) + vc0 * wv.w, 0.f);
    satt += at0;
  }
  ushort4 qo; qo.x = f2b(ax); qo.y = f2b(ay); qo.z = f2b(az); qo.w = f2b(aw);
  *(ushort4*)(Qbf + (size_t)r * D + f0) = qo;
  if (lane == 0) S[r] = satt;
}

// ---- fused GEMM: BM=128 x BN=64 tiles, B staged in LDS via global_load_lds.
// C = [relu]( A1@B1 (+ A2@B2) (+ bias) (+ rowscale*rsvec) ) (+ resid)
__global__ __launch_bounds__(256) void gemm_kernel(
    const ushort* __restrict__ A1, const ushort* __restrict__ B1,
    const ushort* __restrict__ A2, const ushort* __restrict__ B2,
    const float* __restrict__ bias, const float* __restrict__ rowscale,
    const float* __restrict__ rsvec, const float* __restrict__ resid,
    int do_relu, int nblocks,
    float* outF, ushort* outB, int M){
  extern __shared__ ushort ldsB[];
  int tid = threadIdx.x;
  int bn = blockIdx.x % nblocks;
  int bm = blockIdx.x / nblocks;

  stage_chunk(B1 + (size_t)bn * 16384, ldsB, tid);
  if (A2) stage_chunk(B2 + (size_t)bn * 16384, ldsB + 16384, tid);
  __syncthreads();

  int wave = tid >> 6, lane = tid & 63;
  int rbase = bm * 128 + wave * 32;
  int r0 = min(rbase + (lane & 15), M - 1);
  int r1 = min(rbase + 16 + (lane & 15), M - 1);
  int kl = (lane >> 4) * 8;

  f32x4 zero = {0.f, 0.f, 0.f, 0.f};
  f32x4 acc[2][4];
  #pragma unroll
  for (int a = 0; a < 2; ++a)
    #pragma unroll
    for (int b = 0; b < 4; ++b) acc[a][b] = zero;

  gemm_compute(A1, r0, r1, kl, ldsB, lane, acc);
  if (A2) gemm_compute(A2, r0, r1, kl, ldsB + 16384, lane, acc);

  int coll = lane & 15, rl = (lane >> 4) * 4;
  #pragma unroll
  for (int rt = 0; rt < 2; ++rt){
    #pragma unroll
    for (int n = 0; n < 4; ++n){
      int cg = bn * 64 + n * 16 + coll;
      float bc = bias ? bias[cg] : 0.f;
      float vcv = rowscale ? rsvec[cg] : 0.f;
      #pragma unroll
      for (int j = 0; j < 4; ++j){
        int r = rbase + rt * 16 + rl + j;
        if (r < M){
          float v = acc[rt][n][j] + bc;
          if (rowscale) v += rowscale[r] * vcv;
          if (do_relu) v = fmaxf(v, 0.f);
          if (resid) v += resid[(size_t)r * 256 + cg];
          if (outF) outF[(size_t)r * 256 + cg] = v;
          if (outB) outB[(size_t)r * 256 + cg] = f2b(v);
        }
      }
    }
  }
}

extern "C" void kernel_launch(void* const* d_in, const int* in_sizes, int n_in,
                              void* d_out, int out_size, void* d_ws, size_t ws_size,
                              hipStream_t stream){
  const float* h   = (const float*)d_in[0];
  const int*   ei  = (const int*)d_in[1];
  const int*   val = (const int*)d_in[3];
  const float* Wm1 = (const float*)d_in[4];
  const float* bm1 = (const float*)d_in[5];
  const float* Wm2 = (const float*)d_in[6];
  const float* bm2 = (const float*)d_in[7];
  const float* Wu1 = (const float*)d_in[8];
  const float* bu1 = (const float*)d_in[9];
  const float* Wu2 = (const float*)d_in[10];
  const float* bu2 = (const float*)d_in[11];
  const float* Wa1 = (const float*)d_in[12];
  const float* ba1 = (const float*)d_in[13];
  const float* Wa2 = (const float*)d_in[14];
  const float* ba2 = (const float*)d_in[15];
  int N = in_sizes[0] / D;
  int E = in_sizes[1] / 2;
  float* out = (float*)d_out;

  char* ws = (char*)d_ws;
  size_t o = 0;
  auto alloc = [&](size_t bytes)->char*{
    char* p = ws + o; o += (bytes + 255) & ~(size_t)255; return p;
  };
  float*  P1    = (float*) alloc((size_t)N * D * 4);
  ushort* P2    = (ushort*)alloc((size_t)N * D * 2);
  ushort* Hbf   = (ushort*)alloc((size_t)N * D * 2);
  ushort* Qbf   = (ushort*)alloc((size_t)N * D * 2);
  ushort* Hagg  = (ushort*)alloc((size_t)N * D * 2);
  ushort* Tbf   = (ushort*)alloc((size_t)N * D * 2);
  float*  S     = (float*) alloc((size_t)N * 4);
  int*    cur   = (int*)   alloc((size_t)N * 4);
  uint2*  elist = (uint2*) alloc((size_t)N * CAP * 8);
  ushort* pAll  = (ushort*)alloc((size_t)6 * 65536 * 2);
  ushort* pWm1c = pAll;               // [Wm1a|Wm1b] (N=512 cat)
  ushort* pWm2  = pAll + 2 * 65536;
  ushort* pWu1a = pAll + 3 * 65536;
  ushort* pWu1b = pAll + 4 * 65536;
  ushort* pWu2  = pAll + 5 * 65536;

  int NC = N * D;
  prep_kernel<<<2048, 256, 0, stream>>>(h, Hbf, NC, Wm1, Wm2, Wu1, Wu2, pAll, cur, N);

  int mblocks = (N + 127) / 128;

  // D1: G1 (split P1|P2) + edge bucketing
  g1f_kernel<<<1024, 256, 32768, stream>>>(
      Hbf, pWm1c, P1, P2, ei, val, Wa1, ba1, Wa2, ba2, cur, elist,
      N, E, mblocks * 8);

  // D2: per-row aggregation
  phase2_kernel<<<(N + 3) / 4, 256, 0, stream>>>(
      P1, P2, cur, elist, val, Wm1, bm1, Qbf, S, N);

  // D3: Hagg = Q @ Wm2 + S*bm2  (bf16 out)
  gemm_kernel<<<mblocks * 4, 256, 32768, stream>>>(
      Qbf, pWm2, nullptr, nullptr,
      nullptr, S, bm2, nullptr, 0, 4, nullptr, Hagg, N);
  // D4: T = relu(H@Wu1a + Hagg@Wu1b + bu1)  (bf16 out)
  gemm_kernel<<<mblocks * 4, 256, 65536, stream>>>(
      Hbf, pWu1a, Hagg, pWu1b,
      bu1, nullptr, nullptr, nullptr, 1, 4, nullptr, Tbf, N);
  // D5: out = h + T@Wu2 + bu2  (f32 out)
  gemm_kernel<<<mblocks * 4, 256, 32768, stream>>>(
      Tbf, pWu2, nullptr, nullptr,
      bu2, nullptr, nullptr, h, 0, 4, out, nullptr, N);
}

// Round 5
// 92.132 us; speedup vs baseline: 3.7617x; 1.2721x over previous
//
#include <hip/hip_runtime.h>
#include <hip/hip_bf16.h>
#include <math.h>

#define D 256
#define HID 16
#define CAP 96
#define TBM 32

typedef __attribute__((ext_vector_type(8))) short bf16x8;
typedef __attribute__((ext_vector_type(4))) float f32x4;

__device__ __forceinline__ ushort f2b(float x){
  uint u = __float_as_uint(x);
  u = u + 0x7FFFu + ((u >> 16) & 1u);   // round-to-nearest-even
  return (ushort)(u >> 16);
}
__device__ __forceinline__ float b2f(ushort u){ return __uint_as_float(((uint)u) << 16); }

// ---- prep: h->bf16 convert + pack 6 weight matrices + zero cur ----
// packed B layout (nt-major; 64-col tile = contiguous 32KB chunk):
// pb[((nt*8 + kt)*64 + lane)*8 + i] = W[kt*32 + (lane>>4)*8 + i][nt*16 + (lane&15)]
__global__ void prep_kernel(const float* h, ushort* Hbf, int NC,
                            const float* Wm1, const float* Wm2,
                            const float* Wu1, const float* Wu2,
                            ushort* pAll, int* cur, int N){
  int total = NC + 6 * 65536 + N;
  for (int idx = blockIdx.x * blockDim.x + threadIdx.x; idx < total;
       idx += gridDim.x * blockDim.x){
    if (idx < NC){ Hbf[idx] = f2b(h[idx]); continue; }
    int q = idx - NC;
    if (q < 6 * 65536){
      int mat = q >> 16, p = q & 65535;
      int i = p & 7, l = (p >> 3) & 63, kt = (p >> 9) & 7, nt = p >> 12;
      int k = kt * 32 + ((l >> 4) * 8) + i;
      int n = nt * 16 + (l & 15);
      const float* src;
      switch (mat){
        case 0: src = Wm1 + (size_t)k * 256 + n; break;            // Wm1a
        case 1: src = Wm1 + (size_t)(256 + k) * 256 + n; break;    // Wm1b
        case 2: src = Wm2 + (size_t)k * 256 + n; break;
        case 3: src = Wu1 + (size_t)k * 256 + n; break;            // Wu1a
        case 4: src = Wu1 + (size_t)(256 + k) * 256 + n; break;    // Wu1b
        default: src = Wu2 + (size_t)k * 256 + n; break;
      }
      pAll[q] = f2b(*src);
      continue;
    }
    q -= 6 * 65536;
    if (q < N) cur[q] = 0;
  }
}

__device__ __forceinline__ void stage_chunk(const ushort* src, ushort* lds, int tid){
  #pragma unroll
  for (int c = 0; c < 8; ++c)
    __builtin_amdgcn_global_load_lds(
      (const __attribute__((address_space(1))) uint*)(src + tid * 8 + c * 2048),
      (__attribute__((address_space(3))) uint*)(lds + tid * 8 + c * 2048), 16, 0, 0);
}

__device__ __forceinline__ void gemm_compute(const ushort* A, int r0, int r1, int kl,
                                             const ushort* lds, int lane,
                                             f32x4 acc[2][4]){
  const ushort* ap0 = A + (size_t)r0 * 256 + kl;
  const ushort* ap1 = A + (size_t)r1 * 256 + kl;
  #pragma unroll
  for (int kt = 0; kt < 8; ++kt){
    bf16x8 b0 = *(const bf16x8*)(lds + ((size_t)(0 * 8 + kt) * 64 + lane) * 8);
    bf16x8 b1 = *(const bf16x8*)(lds + ((size_t)(1 * 8 + kt) * 64 + lane) * 8);
    bf16x8 b2 = *(const bf16x8*)(lds + ((size_t)(2 * 8 + kt) * 64 + lane) * 8);
    bf16x8 b3 = *(const bf16x8*)(lds + ((size_t)(3 * 8 + kt) * 64 + lane) * 8);
    bf16x8 a0 = *(const bf16x8*)(ap0 + kt * 32);
    bf16x8 a1 = *(const bf16x8*)(ap1 + kt * 32);
    acc[0][0] = __builtin_amdgcn_mfma_f32_16x16x32_bf16(a0, b0, acc[0][0], 0, 0, 0);
    acc[0][1] = __builtin_amdgcn_mfma_f32_16x16x32_bf16(a0, b1, acc[0][1], 0, 0, 0);
    acc[0][2] = __builtin_amdgcn_mfma_f32_16x16x32_bf16(a0, b2, acc[0][2], 0, 0, 0);
    acc[0][3] = __builtin_amdgcn_mfma_f32_16x16x32_bf16(a0, b3, acc[0][3], 0, 0, 0);
    acc[1][0] = __builtin_amdgcn_mfma_f32_16x16x32_bf16(a1, b0, acc[1][0], 0, 0, 0);
    acc[1][1] = __builtin_amdgcn_mfma_f32_16x16x32_bf16(a1, b1, acc[1][1], 0, 0, 0);
    acc[1][2] = __builtin_amdgcn_mfma_f32_16x16x32_bf16(a1, b2, acc[1][2], 0, 0, 0);
    acc[1][3] = __builtin_amdgcn_mfma_f32_16x16x32_bf16(a1, b3, acc[1][3], 0, 0, 0);
  }
}

// ---- G1 + fill fused: [P1|P2] = H @ [Wm1a|Wm1b] (split f32|bf16), then edge bucketing.
__global__ __launch_bounds__(256) void g1f_kernel(
    const ushort* __restrict__ Hbf, const ushort* __restrict__ B,
    float* __restrict__ P1, ushort* __restrict__ P2,
    const int* __restrict__ ei, const int* __restrict__ val,
    const float* __restrict__ Wa1, const float* __restrict__ ba1,
    const float* __restrict__ Wa2, const float* __restrict__ ba2,
    int* __restrict__ cur, uint2* __restrict__ elist,
    int M, int E, int ntiles){
  extern __shared__ ushort lds[];
  int tid = threadIdx.x;
  for (int t = blockIdx.x; t < ntiles; t += gridDim.x){
    int bn = t % 8, bm = t / 8;
    stage_chunk(B + (size_t)bn * 16384, lds, tid);
    __syncthreads();
    int wave = tid >> 6, lane = tid & 63;
    int rbase = bm * 128 + wave * 32;
    int r0 = min(rbase + (lane & 15), M - 1);
    int r1 = min(rbase + 16 + (lane & 15), M - 1);
    int kl = (lane >> 4) * 8;
    f32x4 zero = {0.f, 0.f, 0.f, 0.f};
    f32x4 acc[2][4];
    #pragma unroll
    for (int x = 0; x < 2; ++x)
      #pragma unroll
      for (int y = 0; y < 4; ++y) acc[x][y] = zero;
    gemm_compute(Hbf, r0, r1, kl, lds, lane, acc);
    int coll = lane & 15, rl = (lane >> 4) * 4;
    #pragma unroll
    for (int rt = 0; rt < 2; ++rt){
      #pragma unroll
      for (int n = 0; n < 4; ++n){
        int cg = bn * 64 + n * 16 + coll;
        #pragma unroll
        for (int j = 0; j < 4; ++j){
          int r = rbase + rt * 16 + rl + j;
          if (r < M){
            float v = acc[rt][n][j];
            if (cg < 256) P1[(size_t)r * 256 + cg] = v;
            else P2[(size_t)r * 256 + (cg - 256)] = f2b(v);
          }
        }
      }
    }
    __syncthreads();
  }
  // fill: bucket edges with inline attention MLP
  for (int e = blockIdx.x * 256 + tid; e < E; e += gridDim.x * 256){
    int r = ei[e], c = ei[E + e];
    int vri = val[r], vci = val[c];
    float vr = (float)vri, vc = (float)vci;
    float s = ba2[0];
    #pragma unroll
    for (int j = 0; j < HID; ++j){
      float hj = fmaxf(vr * Wa1[j] + vc * Wa1[HID + j] + ba1[j], 0.f);
      s += hj * Wa2[j];
    }
    float att = 1.f / (1.f + expf(-s));
    int pos = atomicAdd(&cur[r], 1);
    if (pos < CAP)
      elist[(size_t)r * CAP + pos] =
          make_uint2((uint)c | ((uint)vci << 16), __float_as_uint(att));
  }
}

// ---- phase2: per-row edge aggregation, one wave per row, 4-deep gather pipeline.
__global__ __launch_bounds__(256) void phase2_kernel(
    const float* __restrict__ P1, const ushort* __restrict__ P2,
    const int* __restrict__ cur, const uint2* __restrict__ elist,
    const int* __restrict__ val, const float* __restrict__ Wm1,
    const float* __restrict__ bm1,
    ushort* __restrict__ Qbf, float* __restrict__ S, int N){
  int wave = threadIdx.x >> 6, lane = threadIdx.x & 63;
  int r = blockIdx.x * 4 + wave;
  if (r >= N) return;
  int f0 = lane * 4;
  const float* wvr = Wm1 + (size_t)512 * 256;
  const float* wvc = Wm1 + (size_t)513 * 256;
  float4 p1 = *(const float4*)(P1 + (size_t)r * D + f0);
  float4 wr = *(const float4*)(wvr + f0);
  float4 wv = *(const float4*)(wvc + f0);
  float4 bb = *(const float4*)(bm1 + f0);
  float vrf = (float)val[r];
  float bx = p1.x + vrf * wr.x + bb.x;
  float by = p1.y + vrf * wr.y + bb.y;
  float bz = p1.z + vrf * wr.z + bb.z;
  float bw = p1.w + vrf * wr.w + bb.w;
  float ax = 0.f, ay = 0.f, az = 0.f, aw = 0.f, satt = 0.f;
  int dg = min(cur[r], CAP);
  const uint2* el = elist + (size_t)r * CAP;
  int e = 0;
  for (; e + 4 <= dg; e += 4){
    uint2 q0 = el[e], q1 = el[e + 1], q2 = el[e + 2], q3 = el[e + 3];
    ushort4 v0 = *(const ushort4*)(P2 + (size_t)(q0.x & 0xFFFFu) * D + f0);
    ushort4 v1 = *(const ushort4*)(P2 + (size_t)(q1.x & 0xFFFFu) * D + f0);
    ushort4 v2 = *(const ushort4*)(P2 + (size_t)(q2.x & 0xFFFFu) * D + f0);
    ushort4 v3 = *(const ushort4*)(P2 + (size_t)(q3.x & 0xFFFFu) * D + f0);
    float vc0 = (float)(q0.x >> 16), at0 = __uint_as_float(q0.y);
    float vc1 = (float)(q1.x >> 16), at1 = __uint_as_float(q1.y);
    float vc2 = (float)(q2.x >> 16), at2 = __uint_as_float(q2.y);
    float vc3 = (float)(q3.x >> 16), at3 = __uint_as_float(q3.y);
    ax += at0 * fmaxf(bx + b2f(v0.x) + vc0 * wv.x, 0.f);
    ay += at0 * fmaxf(by + b2f(v0.y) + vc0 * wv.y, 0.f);
    az += at0 * fmaxf(bz + b2f(v0.z) + vc0 * wv.z, 0.f);
    aw += at0 * fmaxf(bw + b2f(v0.w) + vc0 * wv.w, 0.f);
    ax += at1 * fmaxf(bx + b2f(v1.x) + vc1 * wv.x, 0.f);
    ay += at1 * fmaxf(by + b2f(v1.y) + vc1 * wv.y, 0.f);
    az += at1 * fmaxf(bz + b2f(v1.z) + vc1 * wv.z, 0.f);
    aw += at1 * fmaxf(bw + b2f(v1.w) + vc1 * wv.w, 0.f);
    ax += at2 * fmaxf(bx + b2f(v2.x) + vc2 * wv.x, 0.f);
    ay += at2 * fmaxf(by + b2f(v2.y) + vc2 * wv.y, 0.f);
    az += at2 * fmaxf(bz + b2f(v2.z) + vc2 * wv.z, 0.f);
    aw += at2 * fmaxf(bw + b2f(v2.w) + vc2 * wv.w, 0.f);
    ax += at3 * fmaxf(bx + b2f(v3.x) + vc3 * wv.x, 0.f);
    ay += at3 * fmaxf(by + b2f(v3.y) + vc3 * wv.y, 0.f);
    az += at3 * fmaxf(bz + b2f(v3.z) + vc3 * wv.z, 0.f);
    aw += at3 * fmaxf(bw + b2f(v3.w) + vc3 * wv.w, 0.f);
    satt += at0 + at1 + at2 + at3;
  }
  for (; e < dg; ++e){
    uint2 q0 = el[e];
    ushort4 v0 = *(const ushort4*)(P2 + (size_t)(q0.x & 0xFFFFu) * D + f0);
    float vc0 = (float)(q0.x >> 16), at0 = __uint_as_float(q0.y);
    ax += at0 * fmaxf(bx + b2f(v0.x) + vc0 * wv.x, 0.f);
    ay += at0 * fmaxf(by + b2f(v0.y) + vc0 * wv.y, 0.f);
    az += at0 * fmaxf(bz + b2f(v0.z) + vc0 * wv.z, 0.f);
    aw += at0 * fmaxf(bw + b2f(v0.w) + vc0 * wv.w, 0.f);
    satt += at0;
  }
  ushort4 qo; qo.x = f2b(ax); qo.y = f2b(ay); qo.z = f2b(az); qo.w = f2b(aw);
  *(ushort4*)(Qbf + (size_t)r * D + f0) = qo;
  if (lane == 0) S[r] = satt;
}

// ---- tail helpers ----
__device__ __forceinline__ void pass_gA(const ushort* __restrict__ A, int arow, int kl,
                                        const ushort* stg, int wn, int lane,
                                        f32x4 acc[2]){
  const ushort* ap = A + (size_t)arow * 256 + kl;
  #pragma unroll
  for (int kt = 0; kt < 8; ++kt){
    bf16x8 a = *(const bf16x8*)(ap + kt * 32);
    bf16x8 b0 = *(const bf16x8*)(stg + (((wn + 0) * 8 + kt) * 64 + lane) * 8);
    bf16x8 b1 = *(const bf16x8*)(stg + (((wn + 1) * 8 + kt) * 64 + lane) * 8);
    acc[0] = __builtin_amdgcn_mfma_f32_16x16x32_bf16(a, b0, acc[0], 0, 0, 0);
    acc[1] = __builtin_amdgcn_mfma_f32_16x16x32_bf16(a, b1, acc[1], 0, 0, 0);
  }
}

// A from swizzled LDS tile [TBM][256] bf16; byte ^= (row&7)<<4
__device__ __forceinline__ void pass_lA(const ushort* tile, int lrow, int kl,
                                        const ushort* stg, int wn, int lane,
                                        f32x4 acc[2]){
  const char* base = (const char*)tile + lrow * 512;
  int sw = (lrow & 7) << 4;
  #pragma unroll
  for (int kt = 0; kt < 8; ++kt){
    int cb = ((kl + kt * 32) * 2) ^ sw;
    bf16x8 a = *(const bf16x8*)(base + cb);
    bf16x8 b0 = *(const bf16x8*)(stg + (((wn + 0) * 8 + kt) * 64 + lane) * 8);
    bf16x8 b1 = *(const bf16x8*)(stg + (((wn + 1) * 8 + kt) * 64 + lane) * 8);
    acc[0] = __builtin_amdgcn_mfma_f32_16x16x32_bf16(a, b0, acc[0], 0, 0, 0);
    acc[1] = __builtin_amdgcn_mfma_f32_16x16x32_bf16(a, b1, acc[1], 0, 0, 0);
  }
}

// ---- tail: Hagg = Q@Wm2 + S*bm2; T = relu(H@Wu1a + Hagg@Wu1b + bu1);
//            out = h + T@Wu2 + bu2.  Row-local chain, TBM rows per block.
__global__ __launch_bounds__(256) void tail_kernel(
    const ushort* __restrict__ Qbf, const ushort* __restrict__ Hbf,
    const float* __restrict__ S, const ushort* __restrict__ pWm2,
    const ushort* __restrict__ pWu1a, const ushort* __restrict__ pWu1b,
    const ushort* __restrict__ pWu2,
    const float* __restrict__ bm2, const float* __restrict__ bu1,
    const float* __restrict__ bu2, const float* __restrict__ h,
    float* __restrict__ out, int M){
  __shared__ ushort stg[16384];        // 32 KB staged B chunk
  __shared__ ushort hag[TBM * 256];    // 16 KB
  __shared__ ushort tt[TBM * 256];     // 16 KB
  int tid = threadIdx.x, w = tid >> 6, lane = tid & 63;
  int row0 = blockIdx.x * TBM;
  int wr = (w & 1) * 16;               // local row base for this wave
  int wn = (w >> 1) * 2;               // nt offset (2 nts per wave) in chunk
  int fr = lane & 15, kl = (lane >> 4) * 8, rq = (lane >> 4) * 4;
  f32x4 zero = {0.f, 0.f, 0.f, 0.f};
  int arow = min(row0 + wr + fr, M - 1);

  // L1: hag = Q@Wm2 + S*bm2
  #pragma unroll 1
  for (int c = 0; c < 4; ++c){
    __syncthreads();
    stage_chunk(pWm2 + (size_t)c * 16384, stg, tid);
    __syncthreads();
    f32x4 acc[2] = {zero, zero};
    pass_gA(Qbf, arow, kl, stg, wn, lane, acc);
    #pragma unroll
    for (int n = 0; n < 2; ++n){
      int cc = c * 64 + (wn + n) * 16 + fr;
      float bv = bm2[cc];
      #pragma unroll
      for (int j = 0; j < 4; ++j){
        int rr = wr + rq + j;
        int gr = min(row0 + rr, M - 1);
        float v = acc[n][j] + S[gr] * bv;
        *(ushort*)((char*)hag + rr * 512 + ((cc * 2) ^ ((rr & 7) << 4))) = f2b(v);
      }
    }
  }

  // L2: tt = relu(H@Wu1a + hag@Wu1b + bu1)
  #pragma unroll 1
  for (int c = 0; c < 4; ++c){
    __syncthreads();
    stage_chunk(pWu1a + (size_t)c * 16384, stg, tid);
    __syncthreads();
    f32x4 acc[2] = {zero, zero};
    pass_gA(Hbf, arow, kl, stg, wn, lane, acc);
    __syncthreads();
    stage_chunk(pWu1b + (size_t)c * 16384, stg, tid);
    __syncthreads();
    pass_lA(hag, wr + fr, kl, stg, wn, lane, acc);
    #pragma unroll
    for (int n = 0; n < 2; ++n){
      int cc = c * 64 + (wn + n) * 16 + fr;
      float bv = bu1[cc];
      #pragma unroll
      for (int j = 0; j < 4; ++j){
        int rr = wr + rq + j;
        float v = fmaxf(acc[n][j] + bv, 0.f);
        *(ushort*)((char*)tt + rr * 512 + ((cc * 2) ^ ((rr & 7) << 4))) = f2b(v);
      }
    }
  }

  // L3: out = h + tt@Wu2 + bu2
  #pragma unroll 1
  for (int c = 0; c < 4; ++c){
    __syncthreads();
    stage_chunk(pWu2 + (size_t)c * 16384, stg, tid);
    __syncthreads();
    f32x4 acc[2] = {zero, zero};
    pass_lA(tt, wr + fr, kl, stg, wn, lane, acc);
    #pragma unroll
    for (int n = 0; n < 2; ++n){
      int cc = c * 64 + (wn + n) * 16 + fr;
      float bv = bu2[cc];
      #pragma unroll
      for (int j = 0; j < 4; ++j){
        int rr = wr + rq + j;
        int gr = row0 + rr;
        if (gr < M)
          out[(size_t)gr * 256 + cc] = acc[n][j] + bv + h[(size_t)gr * 256 + cc];
      }
    }
  }
}

extern "C" void kernel_launch(void* const* d_in, const int* in_sizes, int n_in,
                              void* d_out, int out_size, void* d_ws, size_t ws_size,
                              hipStream_t stream){
  const float* h   = (const float*)d_in[0];
  const int*   ei  = (const int*)d_in[1];
  const int*   val = (const int*)d_in[3];
  const float* Wm1 = (const float*)d_in[4];
  const float* bm1 = (const float*)d_in[5];
  const float* Wm2 = (const float*)d_in[6];
  const float* bm2 = (const float*)d_in[7];
  const float* Wu1 = (const float*)d_in[8];
  const float* bu1 = (const float*)d_in[9];
  const float* Wu2 = (const float*)d_in[10];
  const float* bu2 = (const float*)d_in[11];
  const float* Wa1 = (const float*)d_in[12];
  const float* ba1 = (const float*)d_in[13];
  const float* Wa2 = (const float*)d_in[14];
  const float* ba2 = (const float*)d_in[15];
  int N = in_sizes[0] / D;
  int E = in_sizes[1] / 2;
  float* out = (float*)d_out;

  char* ws = (char*)d_ws;
  size_t o = 0;
  auto alloc = [&](size_t bytes)->char*{
    char* p = ws + o; o += (bytes + 255) & ~(size_t)255; return p;
  };
  float*  P1    = (float*) alloc((size_t)N * D * 4);
  ushort* P2    = (ushort*)alloc((size_t)N * D * 2);
  ushort* Hbf   = (ushort*)alloc((size_t)N * D * 2);
  ushort* Qbf   = (ushort*)alloc((size_t)N * D * 2);
  float*  S     = (float*) alloc((size_t)N * 4);
  int*    cur   = (int*)   alloc((size_t)N * 4);
  uint2*  elist = (uint2*) alloc((size_t)N * CAP * 8);
  ushort* pAll  = (ushort*)alloc((size_t)6 * 65536 * 2);
  ushort* pWm1c = pAll;               // [Wm1a|Wm1b] (N=512 cat)
  ushort* pWm2  = pAll + 2 * 65536;
  ushort* pWu1a = pAll + 3 * 65536;
  ushort* pWu1b = pAll + 4 * 65536;
  ushort* pWu2  = pAll + 5 * 65536;

  int NC = N * D;
  prep_kernel<<<2048, 256, 0, stream>>>(h, Hbf, NC, Wm1, Wm2, Wu1, Wu2, pAll, cur, N);

  int mblocks = (N + 127) / 128;

  // D2: G1 (split P1|P2) + edge bucketing
  g1f_kernel<<<1024, 256, 32768, stream>>>(
      Hbf, pWm1c, P1, P2, ei, val, Wa1, ba1, Wa2, ba2, cur, elist,
      N, E, mblocks * 8);

  // D3: per-row aggregation
  phase2_kernel<<<(N + 3) / 4, 256, 0, stream>>>(
      P1, P2, cur, elist, val, Wm1, bm1, Qbf, S, N);

  // D4: fused row-local tail (Hagg -> T -> out)
  tail_kernel<<<(N + TBM - 1) / TBM, 256, 0, stream>>>(
      Qbf, Hbf, S, pWm2, pWu1a, pWu1b, pWu2, bm2, bu1, bu2, h, out, N);
}